// Round 23
// baseline (154.273 us; speedup 1.0000x reference)
//
#include <hip/hip_runtime.h>
#include <hip/hip_bf16.h>

#define TPB 512
#define NCODES 1024
#define DIMS 256
#define PIXB 64
#define DELTA 3.0f    // screening margin (bf16 worst-case dot error ~1.3; 3.0 is safe)
#define CAP 16        // candidate capacity per pixel (overflow -> full rescan)

typedef __attribute__((ext_vector_type(8))) short bf16x8;
typedef __attribute__((ext_vector_type(4))) float f32x4;

// prep: eb_t = bf16(emb) PRE-TILED in 8-wave K-loop consumption order:
//   tile(st, w8) = contiguous 1024 ushorts (2 KB): [j(0..3)][code cl(0..31)][8 dims]
//   st = (c>>8)*8 + (d>>5),  w8 = (c>>5)&7,  cl = c&31,  j = (d>>3)&3, e = d&7.
// e2[c] = sum_d emb[c][d]^2 (exact fp32)
__global__ __launch_bounds__(256) void prep_kernel(const float* __restrict__ emb,
                                                   ushort* __restrict__ eb,
                                                   float* __restrict__ e2) {
    const int w = threadIdx.x >> 6;
    const int l = threadIdx.x & 63;
    const int c = blockIdx.x * 4 + w;
    float4 v = *(const float4*)(emb + (size_t)c * DIMS + 4 * l);
    __hip_bfloat16 h0 = __float2bfloat16(v.x), h1 = __float2bfloat16(v.y);
    __hip_bfloat16 h2 = __float2bfloat16(v.z), h3 = __float2bfloat16(v.w);
    ushort4 u;
    u.x = *(ushort*)&h0; u.y = *(ushort*)&h1; u.z = *(ushort*)&h2; u.w = *(ushort*)&h3;
    const int st = (c >> 8) * 8 + (l >> 3);
    const int w8 = (c >> 5) & 7;
    const int cl = c & 31;
    const int j  = (l >> 1) & 3;
    const int e  = (4 * l) & 7;
    *(ushort4*)(eb + (((size_t)(st * 8 + w8) << 10) + (j << 8) + cl * 8 + e)) = u;
    float sq = v.x * v.x + v.y * v.y + v.z * v.z + v.w * v.w;
#pragma unroll
    for (int off = 1; off < 64; off <<= 1) sq += __shfl_xor(sq, off);
    if (l == 0) e2[c] = sq;
}

// FINAL configuration (R16/R18-R22-proven, ~151-155us total / ~84us vq):
// register-path phase 1, depth-4 E prefetch from pre-tiled codebook, barriered
// epilogue, CAP 16, LDS 45056 (3 blocks/CU), VGPR 64.
// Session constraints (documented for future work):
//  - Barrier-free chunk-1..3 epilogue (rmin variant): deterministic ~6x SLOWER
//    (R14 same-run A/B: 80 vs 490us). Keep the barriered epilogue.
//  - LDS 40960 (4 blocks x 512 thr = exactly-full CU): deterministic ~6x mode
//    (R10, R17). Keep LDS > 40960 so at most 3 blocks are resident.
//  - Pathology signature: Occ ~5%, uniform ~6x dilation, byte counters flat.
//    Mechanism unresolved (candidates: hidden scratch reservation gating wave
//    launch, or full-occupancy dispatch pathology). Needs disasm +
//    Private_Segment_Size visibility to diagnose.
//  - Next real lever (untried, landmine-class): 32x32x16 MFMA restructure to
//    halve phase-2 instruction count (issue-bound hypothesis).
__global__ __launch_bounds__(TPB, 3) void vq_kernel(const float* __restrict__ z,
                                                    const float* __restrict__ emb,
                                                    const ushort* __restrict__ eb,
                                                    const float* __restrict__ e2g,
                                                    int* __restrict__ out) {
    __shared__ __align__(16) ushort xs2[32 * 64 * 8];  // 32768 B
    __shared__ __align__(16) char pool[12288];         // epilogue overlay only

    float* const wmin   = (float*)pool;                 // 8*64 f32   @0    (2048 B)
    float* const minval = (float*)(pool + 2048);        // 64 f32     @2048 (256 B)
    int*   const cnt    = (int*)(pool + 2304);          // 64 int     @2304 (256 B)
    int*   const cand   = (int*)(pool + 2560);          // 64*16 int  @2560 (4096 B)
    float* const scand  = (float*)(pool + 6656);        // 64*16 f32  @6656 (4096 B) -> end 10752 <= 12288

    const int tid = threadIdx.x;
    const int w   = tid >> 6;     // wave 0..7 (owns 32 codes per chunk)
    const int L   = tid & 63;
    const int col = L & 15;       // MFMA col (= pixel within n-tile)
    const int q   = L >> 4;       // MFMA quad
    const int pixbase = blockIdx.x * PIXB;
    const int t  = pixbase >> 12;
    const int n0 = pixbase & 4095;

    // ---- phase 1: REGISTER-PATH z staging. Wave w owns granules w*4..w*4+3
    // (granule g = dims 8g..8g+7). Lane L handles px L: 8 coalesced loads ->
    // bf16 pack -> one contiguous 16 B ds_write_b128. 32 independent loads/wave.
    {
        const float* zb = z + (((size_t)t * DIMS) << 12) + n0 + L;
#pragma unroll
        for (int k = 0; k < 4; ++k) {
            const int g = w * 4 + k;
            float v0 = zb[((size_t)(g * 8 + 0) << 12)];
            float v1 = zb[((size_t)(g * 8 + 1) << 12)];
            float v2 = zb[((size_t)(g * 8 + 2) << 12)];
            float v3 = zb[((size_t)(g * 8 + 3) << 12)];
            float v4 = zb[((size_t)(g * 8 + 4) << 12)];
            float v5 = zb[((size_t)(g * 8 + 5) << 12)];
            float v6 = zb[((size_t)(g * 8 + 6) << 12)];
            float v7 = zb[((size_t)(g * 8 + 7) << 12)];
            __hip_bfloat16 b0 = __float2bfloat16(v0), b1 = __float2bfloat16(v1);
            __hip_bfloat16 b2 = __float2bfloat16(v2), b3 = __float2bfloat16(v3);
            __hip_bfloat16 b4 = __float2bfloat16(v4), b5 = __float2bfloat16(v5);
            __hip_bfloat16 b6 = __float2bfloat16(v6), b7 = __float2bfloat16(v7);
            ushort u[8] = { *(ushort*)&b0, *(ushort*)&b1, *(ushort*)&b2, *(ushort*)&b3,
                            *(ushort*)&b4, *(ushort*)&b5, *(ushort*)&b6, *(ushort*)&b7 };
            *(bf16x8*)&xs2[(size_t)((g * 64 + L) * 8)] = *(bf16x8*)u;
        }
    }

    // ---- phase 2 prologue: depth-4 E prefetch straight to registers ----
#define LOADT(a0_, a1_, st_) do {                                                 \
        const ushort* _et = eb + (((size_t)((st_) * 8 + w)) << 10)                \
                               + (q << 8) + (col << 3);                           \
        a0_ = *(const bf16x8*)_et;                                                \
        a1_ = *(const bf16x8*)(_et + 128);                                        \
    } while (0)

    bf16x8 pf[4][2];
    LOADT(pf[0][0], pf[0][1], 0);
    LOADT(pf[1][0], pf[1][1], 1);
    LOADT(pf[2][0], pf[2][1], 2);
    LOADT(pf[3][0], pf[3][1], 3);

    __syncthreads();                                   // xs2 complete
    if (tid < 64) { minval[tid] = 3.4e38f; cnt[tid] = 0; }
    // (visible to all at the chunk-0 epilogue barrier)

    // ---- phase 2: MFMA screening; E global->regs (depth-4), X from LDS ----
#pragma unroll 1
    for (int cc = 0; cc < 4; ++cc) {
        f32x4 acc[2][4];
#pragma unroll
        for (int mt = 0; mt < 2; ++mt)
#pragma unroll
            for (int nt = 0; nt < 4; ++nt) acc[mt][nt] = (f32x4){0.f, 0.f, 0.f, 0.f};

#pragma unroll
        for (int kc = 0; kc < 8; ++kc) {
            const int s = cc * 8 + kc;
            bf16x8 a0 = pf[kc & 3][0];
            bf16x8 a1 = pf[kc & 3][1];
            bf16x8 bfr[4];
#pragma unroll
            for (int nt = 0; nt < 4; ++nt)
                bfr[nt] = *(const bf16x8*)&xs2[(size_t)(((kc * 4 + q) * 64 + nt * 16 + col) * 8)];
            {   // continuous prefetch 4 steps ahead (flows across chunk boundary)
                const int st = (s + 4 < 31) ? s + 4 : 31;
                LOADT(pf[kc & 3][0], pf[kc & 3][1], st);
            }
            __builtin_amdgcn_s_setprio(1);
#pragma unroll
            for (int nt = 0; nt < 4; ++nt)
                acc[0][nt] = __builtin_amdgcn_mfma_f32_16x16x32_bf16(
                    a0, bfr[nt], acc[0][nt], 0, 0, 0);
#pragma unroll
            for (int nt = 0; nt < 4; ++nt)
                acc[1][nt] = __builtin_amdgcn_mfma_f32_16x16x32_bf16(
                    a1, bfr[nt], acc[1][nt], 0, 0, 0);
            __builtin_amdgcn_s_setprio(0);
        }

        // epilogue: s = e2[c] - 2*dot ; C layout: col=lane&15 (px), row=q*4+r (code)
        f32x4 e4[2];
#pragma unroll
        for (int mt = 0; mt < 2; ++mt)
            e4[mt] = *(const f32x4*)(e2g + cc * 256 + w * 32 + mt * 16 + q * 4);

        // 1) per-(wave,px) chunk min
#pragma unroll
        for (int nt = 0; nt < 4; ++nt) {
            float m = 3.4e38f;
#pragma unroll
            for (int mt = 0; mt < 2; ++mt)
#pragma unroll
                for (int r = 0; r < 4; ++r) {
                    float s = e4[mt][r] - 2.f * acc[mt][nt][r];
                    m = fminf(m, s);
                }
            m = fminf(m, __shfl_xor(m, 16));
            m = fminf(m, __shfl_xor(m, 32));
            wmin[w * 64 + nt * 16 + col] = m;    // all q-copies write same value
        }
        __syncthreads();
        if (tid < 64) {
            float m = minval[tid];
#pragma unroll
            for (int ww = 0; ww < 8; ++ww) m = fminf(m, wmin[ww * 64 + tid]);
            minval[tid] = m;
        }
        __syncthreads();
        // 2) candidate scan (running-min threshold => superset of final candidate set)
#pragma unroll
        for (int nt = 0; nt < 4; ++nt) {
            const int px = nt * 16 + col;
            const float thr = minval[px] + DELTA;
#pragma unroll
            for (int mt = 0; mt < 2; ++mt)
#pragma unroll
                for (int r = 0; r < 4; ++r) {
                    float s = e4[mt][r] - 2.f * acc[mt][nt][r];
                    if (s <= thr) {
                        int pos = atomicAdd(&cnt[px], 1);
                        if (pos < CAP) {
                            cand[px * CAP + pos]  = cc * 256 + w * 32 + mt * 16 + q * 4 + r;
                            scand[px * CAP + pos] = s;
                        }
                    }
                }
        }
    }
    __syncthreads();

    // ---- phase 3: final filter at the TRUE screened min, then exact rescore of
    // survivors only. wave w does px w*8..+7.
#pragma unroll 1
    for (int pi = 0; pi < 8; ++pi) {
        const int px = w * 8 + pi;
        const int n  = cnt[px];
        if (n <= CAP) {
            const float thr = minval[px] + DELTA;
            bool surv = (L < n) && (scand[px * CAP + L] <= thr);
            unsigned long long mask = __ballot(surv);
            if (__popcll(mask) == 1) {
                if (L == 0) out[pixbase + px] = cand[px * CAP + (__ffsll(mask) - 1)];
                continue;
            }
            const float* zp = z + (((size_t)t * DIMS + 4 * L) << 12) + n0 + px;
            float x0 = zp[0];
            float x1 = zp[(size_t)1 << 12];
            float x2 = zp[(size_t)2 << 12];
            float x3 = zp[(size_t)3 << 12];
            float bs = 3.4e38f;
            int   bi = 0;
            unsigned long long mm = mask;
            while (mm) {
                int k = __ffsll(mm) - 1; mm &= mm - 1;
                int c = cand[px * CAP + k];
                float4 ev = *(const float4*)(emb + (size_t)c * DIMS + 4 * L);
                float p = x0 * ev.x + x1 * ev.y + x2 * ev.z + x3 * ev.w;
#pragma unroll
                for (int off = 1; off < 64; off <<= 1) p += __shfl_xor(p, off);
                float s = e2g[c] - 2.f * p;
                if (s < bs || (s == bs && c < bi)) { bs = s; bi = c; }
            }
            if (L == 0) out[pixbase + px] = bi;
        } else {
            const float* zp = z + (((size_t)t * DIMS + 4 * L) << 12) + n0 + px;
            float x0 = zp[0];
            float x1 = zp[(size_t)1 << 12];
            float x2 = zp[(size_t)2 << 12];
            float x3 = zp[(size_t)3 << 12];
            float bs = 3.4e38f;
            int   bi = 0;
            for (int c = 0; c < NCODES; ++c) {
                float4 ev = *(const float4*)(emb + (size_t)c * DIMS + 4 * L);
                float p = x0 * ev.x + x1 * ev.y + x2 * ev.z + x3 * ev.w;
#pragma unroll
                for (int off = 1; off < 64; off <<= 1) p += __shfl_xor(p, off);
                float s = e2g[c] - 2.f * p;
                if (s < bs || (s == bs && c < bi)) { bs = s; bi = c; }
            }
            if (L == 0) out[pixbase + px] = bi;
        }
    }
#undef LOADT
}

extern "C" void kernel_launch(void* const* d_in, const int* in_sizes, int n_in,
                              void* d_out, int out_size, void* d_ws, size_t ws_size,
                              hipStream_t stream) {
    const float* z   = (const float*)d_in[0];   // (16,256,64,64) fp32
    const float* emb = (const float*)d_in[1];   // (1024,256) fp32
    int* out = (int*)d_out;                     // (16,64,64) int32

    ushort* eb = (ushort*)d_ws;                          // tiled bf16 codebook, 512 KB
    float*  e2 = (float*)((char*)d_ws + (size_t)NCODES * DIMS * sizeof(ushort)); // 4 KB

    prep_kernel<<<256, 256, 0, stream>>>(emb, eb, e2);
    vq_kernel<<<(16 * 64 * 64) / PIXB, TPB, 0, stream>>>(z, emb, eb, e2, out);
}

// Round 24
// 151.065 us; speedup vs baseline: 1.0212x; 1.0212x over previous
//
#include <hip/hip_runtime.h>
#include <hip/hip_bf16.h>

#define TPB 512
#define NCODES 1024
#define DIMS 256
#define PIXB 64
#define DELTA 3.0f    // screening margin (bf16 worst-case dot error ~1.3; 3.0 is safe)
#define CAP 16        // candidate capacity per pixel (overflow -> full rescan)

typedef __attribute__((ext_vector_type(8))) short bf16x8;
typedef __attribute__((ext_vector_type(4))) float f32x4;

// prep: eb_t = bf16(emb) PRE-TILED in 8-wave K-loop consumption order:
//   tile(st, w8) = contiguous 1024 ushorts (2 KB): [j(0..3)][code cl(0..31)][8 dims]
//   st = (c>>8)*8 + (d>>5),  w8 = (c>>5)&7,  cl = c&31,  j = (d>>3)&3, e = d&7.
// e2[c] = sum_d emb[c][d]^2 (exact fp32)
__global__ __launch_bounds__(256) void prep_kernel(const float* __restrict__ emb,
                                                   ushort* __restrict__ eb,
                                                   float* __restrict__ e2) {
    const int w = threadIdx.x >> 6;
    const int l = threadIdx.x & 63;
    const int c = blockIdx.x * 4 + w;
    float4 v = *(const float4*)(emb + (size_t)c * DIMS + 4 * l);
    __hip_bfloat16 h0 = __float2bfloat16(v.x), h1 = __float2bfloat16(v.y);
    __hip_bfloat16 h2 = __float2bfloat16(v.z), h3 = __float2bfloat16(v.w);
    ushort4 u;
    u.x = *(ushort*)&h0; u.y = *(ushort*)&h1; u.z = *(ushort*)&h2; u.w = *(ushort*)&h3;
    const int st = (c >> 8) * 8 + (l >> 3);
    const int w8 = (c >> 5) & 7;
    const int cl = c & 31;
    const int j  = (l >> 1) & 3;
    const int e  = (4 * l) & 7;
    *(ushort4*)(eb + (((size_t)(st * 8 + w8) << 10) + (j << 8) + cl * 8 + e)) = u;
    float sq = v.x * v.x + v.y * v.y + v.z * v.z + v.w * v.w;
#pragma unroll
    for (int off = 1; off < 64; off <<= 1) sq += __shfl_xor(sq, off);
    if (l == 0) e2[c] = sq;
}

// FINAL configuration (R16/R18-R23-proven, ~151-155us total / ~84us vq):
// register-path phase 1, depth-4 E prefetch from pre-tiled codebook, barriered
// epilogue, CAP 16, LDS 45056 (3 blocks/CU), VGPR 64.
// Session constraints (documented for future work):
//  - Barrier-free chunk-1..3 epilogue (rmin variant): deterministic ~6x SLOWER
//    (R14 same-run A/B: 80 vs 490us). Keep the barriered epilogue.
//  - LDS 40960 (4 blocks x 512 thr = exactly-full CU): deterministic ~6x mode
//    (R10, R17). Keep LDS > 40960 so at most 3 blocks are resident.
//  - Pathology signature: Occ ~5%, uniform ~6x dilation, byte counters flat.
//    Mechanism unresolved (candidates: hidden scratch reservation gating wave
//    launch, or full-occupancy dispatch pathology). Needs disasm +
//    Private_Segment_Size visibility to diagnose.
//  - Next real lever (untried, landmine-class): 32x32x16 MFMA restructure to
//    halve phase-2 instruction count (issue-bound hypothesis).
__global__ __launch_bounds__(TPB, 3) void vq_kernel(const float* __restrict__ z,
                                                    const float* __restrict__ emb,
                                                    const ushort* __restrict__ eb,
                                                    const float* __restrict__ e2g,
                                                    int* __restrict__ out) {
    __shared__ __align__(16) ushort xs2[32 * 64 * 8];  // 32768 B
    __shared__ __align__(16) char pool[12288];         // epilogue overlay only

    float* const wmin   = (float*)pool;                 // 8*64 f32   @0    (2048 B)
    float* const minval = (float*)(pool + 2048);        // 64 f32     @2048 (256 B)
    int*   const cnt    = (int*)(pool + 2304);          // 64 int     @2304 (256 B)
    int*   const cand   = (int*)(pool + 2560);          // 64*16 int  @2560 (4096 B)
    float* const scand  = (float*)(pool + 6656);        // 64*16 f32  @6656 (4096 B) -> end 10752 <= 12288

    const int tid = threadIdx.x;
    const int w   = tid >> 6;     // wave 0..7 (owns 32 codes per chunk)
    const int L   = tid & 63;
    const int col = L & 15;       // MFMA col (= pixel within n-tile)
    const int q   = L >> 4;       // MFMA quad
    const int pixbase = blockIdx.x * PIXB;
    const int t  = pixbase >> 12;
    const int n0 = pixbase & 4095;

    // ---- phase 1: REGISTER-PATH z staging. Wave w owns granules w*4..w*4+3
    // (granule g = dims 8g..8g+7). Lane L handles px L: 8 coalesced loads ->
    // bf16 pack -> one contiguous 16 B ds_write_b128. 32 independent loads/wave.
    {
        const float* zb = z + (((size_t)t * DIMS) << 12) + n0 + L;
#pragma unroll
        for (int k = 0; k < 4; ++k) {
            const int g = w * 4 + k;
            float v0 = zb[((size_t)(g * 8 + 0) << 12)];
            float v1 = zb[((size_t)(g * 8 + 1) << 12)];
            float v2 = zb[((size_t)(g * 8 + 2) << 12)];
            float v3 = zb[((size_t)(g * 8 + 3) << 12)];
            float v4 = zb[((size_t)(g * 8 + 4) << 12)];
            float v5 = zb[((size_t)(g * 8 + 5) << 12)];
            float v6 = zb[((size_t)(g * 8 + 6) << 12)];
            float v7 = zb[((size_t)(g * 8 + 7) << 12)];
            __hip_bfloat16 b0 = __float2bfloat16(v0), b1 = __float2bfloat16(v1);
            __hip_bfloat16 b2 = __float2bfloat16(v2), b3 = __float2bfloat16(v3);
            __hip_bfloat16 b4 = __float2bfloat16(v4), b5 = __float2bfloat16(v5);
            __hip_bfloat16 b6 = __float2bfloat16(v6), b7 = __float2bfloat16(v7);
            ushort u[8] = { *(ushort*)&b0, *(ushort*)&b1, *(ushort*)&b2, *(ushort*)&b3,
                            *(ushort*)&b4, *(ushort*)&b5, *(ushort*)&b6, *(ushort*)&b7 };
            *(bf16x8*)&xs2[(size_t)((g * 64 + L) * 8)] = *(bf16x8*)u;
        }
    }

    // ---- phase 2 prologue: depth-4 E prefetch straight to registers ----
#define LOADT(a0_, a1_, st_) do {                                                 \
        const ushort* _et = eb + (((size_t)((st_) * 8 + w)) << 10)                \
                               + (q << 8) + (col << 3);                           \
        a0_ = *(const bf16x8*)_et;                                                \
        a1_ = *(const bf16x8*)(_et + 128);                                        \
    } while (0)

    bf16x8 pf[4][2];
    LOADT(pf[0][0], pf[0][1], 0);
    LOADT(pf[1][0], pf[1][1], 1);
    LOADT(pf[2][0], pf[2][1], 2);
    LOADT(pf[3][0], pf[3][1], 3);

    __syncthreads();                                   // xs2 complete
    if (tid < 64) { minval[tid] = 3.4e38f; cnt[tid] = 0; }
    // (visible to all at the chunk-0 epilogue barrier)

    // ---- phase 2: MFMA screening; E global->regs (depth-4), X from LDS ----
#pragma unroll 1
    for (int cc = 0; cc < 4; ++cc) {
        f32x4 acc[2][4];
#pragma unroll
        for (int mt = 0; mt < 2; ++mt)
#pragma unroll
            for (int nt = 0; nt < 4; ++nt) acc[mt][nt] = (f32x4){0.f, 0.f, 0.f, 0.f};

#pragma unroll
        for (int kc = 0; kc < 8; ++kc) {
            const int s = cc * 8 + kc;
            bf16x8 a0 = pf[kc & 3][0];
            bf16x8 a1 = pf[kc & 3][1];
            bf16x8 bfr[4];
#pragma unroll
            for (int nt = 0; nt < 4; ++nt)
                bfr[nt] = *(const bf16x8*)&xs2[(size_t)(((kc * 4 + q) * 64 + nt * 16 + col) * 8)];
            {   // continuous prefetch 4 steps ahead (flows across chunk boundary)
                const int st = (s + 4 < 31) ? s + 4 : 31;
                LOADT(pf[kc & 3][0], pf[kc & 3][1], st);
            }
            __builtin_amdgcn_s_setprio(1);
#pragma unroll
            for (int nt = 0; nt < 4; ++nt)
                acc[0][nt] = __builtin_amdgcn_mfma_f32_16x16x32_bf16(
                    a0, bfr[nt], acc[0][nt], 0, 0, 0);
#pragma unroll
            for (int nt = 0; nt < 4; ++nt)
                acc[1][nt] = __builtin_amdgcn_mfma_f32_16x16x32_bf16(
                    a1, bfr[nt], acc[1][nt], 0, 0, 0);
            __builtin_amdgcn_s_setprio(0);
        }

        // epilogue: s = e2[c] - 2*dot ; C layout: col=lane&15 (px), row=q*4+r (code)
        f32x4 e4[2];
#pragma unroll
        for (int mt = 0; mt < 2; ++mt)
            e4[mt] = *(const f32x4*)(e2g + cc * 256 + w * 32 + mt * 16 + q * 4);

        // 1) per-(wave,px) chunk min
#pragma unroll
        for (int nt = 0; nt < 4; ++nt) {
            float m = 3.4e38f;
#pragma unroll
            for (int mt = 0; mt < 2; ++mt)
#pragma unroll
                for (int r = 0; r < 4; ++r) {
                    float s = e4[mt][r] - 2.f * acc[mt][nt][r];
                    m = fminf(m, s);
                }
            m = fminf(m, __shfl_xor(m, 16));
            m = fminf(m, __shfl_xor(m, 32));
            wmin[w * 64 + nt * 16 + col] = m;    // all q-copies write same value
        }
        __syncthreads();
        if (tid < 64) {
            float m = minval[tid];
#pragma unroll
            for (int ww = 0; ww < 8; ++ww) m = fminf(m, wmin[ww * 64 + tid]);
            minval[tid] = m;
        }
        __syncthreads();
        // 2) candidate scan (running-min threshold => superset of final candidate set)
#pragma unroll
        for (int nt = 0; nt < 4; ++nt) {
            const int px = nt * 16 + col;
            const float thr = minval[px] + DELTA;
#pragma unroll
            for (int mt = 0; mt < 2; ++mt)
#pragma unroll
                for (int r = 0; r < 4; ++r) {
                    float s = e4[mt][r] - 2.f * acc[mt][nt][r];
                    if (s <= thr) {
                        int pos = atomicAdd(&cnt[px], 1);
                        if (pos < CAP) {
                            cand[px * CAP + pos]  = cc * 256 + w * 32 + mt * 16 + q * 4 + r;
                            scand[px * CAP + pos] = s;
                        }
                    }
                }
        }
    }
    __syncthreads();

    // ---- phase 3: final filter at the TRUE screened min, then exact rescore of
    // survivors only. wave w does px w*8..+7.
#pragma unroll 1
    for (int pi = 0; pi < 8; ++pi) {
        const int px = w * 8 + pi;
        const int n  = cnt[px];
        if (n <= CAP) {
            const float thr = minval[px] + DELTA;
            bool surv = (L < n) && (scand[px * CAP + L] <= thr);
            unsigned long long mask = __ballot(surv);
            if (__popcll(mask) == 1) {
                if (L == 0) out[pixbase + px] = cand[px * CAP + (__ffsll(mask) - 1)];
                continue;
            }
            const float* zp = z + (((size_t)t * DIMS + 4 * L) << 12) + n0 + px;
            float x0 = zp[0];
            float x1 = zp[(size_t)1 << 12];
            float x2 = zp[(size_t)2 << 12];
            float x3 = zp[(size_t)3 << 12];
            float bs = 3.4e38f;
            int   bi = 0;
            unsigned long long mm = mask;
            while (mm) {
                int k = __ffsll(mm) - 1; mm &= mm - 1;
                int c = cand[px * CAP + k];
                float4 ev = *(const float4*)(emb + (size_t)c * DIMS + 4 * L);
                float p = x0 * ev.x + x1 * ev.y + x2 * ev.z + x3 * ev.w;
#pragma unroll
                for (int off = 1; off < 64; off <<= 1) p += __shfl_xor(p, off);
                float s = e2g[c] - 2.f * p;
                if (s < bs || (s == bs && c < bi)) { bs = s; bi = c; }
            }
            if (L == 0) out[pixbase + px] = bi;
        } else {
            const float* zp = z + (((size_t)t * DIMS + 4 * L) << 12) + n0 + px;
            float x0 = zp[0];
            float x1 = zp[(size_t)1 << 12];
            float x2 = zp[(size_t)2 << 12];
            float x3 = zp[(size_t)3 << 12];
            float bs = 3.4e38f;
            int   bi = 0;
            for (int c = 0; c < NCODES; ++c) {
                float4 ev = *(const float4*)(emb + (size_t)c * DIMS + 4 * L);
                float p = x0 * ev.x + x1 * ev.y + x2 * ev.z + x3 * ev.w;
#pragma unroll
                for (int off = 1; off < 64; off <<= 1) p += __shfl_xor(p, off);
                float s = e2g[c] - 2.f * p;
                if (s < bs || (s == bs && c < bi)) { bs = s; bi = c; }
            }
            if (L == 0) out[pixbase + px] = bi;
        }
    }
#undef LOADT
}

extern "C" void kernel_launch(void* const* d_in, const int* in_sizes, int n_in,
                              void* d_out, int out_size, void* d_ws, size_t ws_size,
                              hipStream_t stream) {
    const float* z   = (const float*)d_in[0];   // (16,256,64,64) fp32
    const float* emb = (const float*)d_in[1];   // (1024,256) fp32
    int* out = (int*)d_out;                     // (16,64,64) int32

    ushort* eb = (ushort*)d_ws;                          // tiled bf16 codebook, 512 KB
    float*  e2 = (float*)((char*)d_ws + (size_t)NCODES * DIMS * sizeof(ushort)); // 4 KB

    prep_kernel<<<256, 256, 0, stream>>>(emb, eb, e2);
    vq_kernel<<<(16 * 64 * 64) / PIXB, TPB, 0, stream>>>(z, emb, eb, e2, out);
}